// Round 22
// baseline (349.018 us; speedup 1.0000x reference)
//
#include <hip/hip_runtime.h>
#include <hip/hip_bf16.h>
#include <cstdint>

#define TOK 100352
#define HID 384
#define NQKV 1152
#define NHEADS 12
#define HDIM 32

typedef __attribute__((ext_vector_type(8))) short bhalf8;
typedef __attribute__((ext_vector_type(4))) float f32x4;

__device__ __forceinline__ ushort f2bf(float f) {
  uint32_t u = __float_as_uint(f);
  return (ushort)((u + 0x7FFFu + ((u >> 16) & 1u)) >> 16);
}

__device__ __forceinline__ void gload_lds16(const ushort* g, ushort* l) {
  __builtin_amdgcn_global_load_lds(
      (const __attribute__((address_space(1))) unsigned int*)g,
      (__attribute__((address_space(3))) unsigned int*)l, 16, 0, 0);
}

__device__ __forceinline__ uint32_t cvtpk(float a, float b) {
  uint32_t r;
  asm("v_cvt_pk_bf16_f32 %0, %1, %2" : "=v"(r) : "v"(a), "v"(b));
  return r;
}

// ---- pre-pass: fp32 -> bf16, vectorized 8/thread ----
__global__ __launch_bounds__(256)
void cvt_bf16(const float* __restrict__ in, ushort* __restrict__ out, const int n8) {
  const int i = blockIdx.x * 256 + threadIdx.x;
  if (i >= n8) return;
  const float4 f0 = ((const float4*)in)[(size_t)i * 2];
  const float4 f1 = ((const float4*)in)[(size_t)i * 2 + 1];
  bhalf8 v;
  v[0] = (short)f2bf(f0.x); v[1] = (short)f2bf(f0.y);
  v[2] = (short)f2bf(f0.z); v[3] = (short)f2bf(f0.w);
  v[4] = (short)f2bf(f1.x); v[5] = (short)f2bf(f1.y);
  v[6] = (short)f2bf(f1.z); v[7] = (short)f2bf(f1.w);
  ((bhalf8*)out)[i] = v;
}

// ---- pre-pass: [R][C] fp32 -> [C][R] bf16 (tiny weights) ----
__global__ __launch_bounds__(256)
void transpose_cvt(const float* __restrict__ in, ushort* __restrict__ out,
                   const int R, const int C) {
  const int i = blockIdx.x * 256 + threadIdx.x;
  if (i >= R * C) return;
  const int r = i % R, c = i / R;
  out[i] = f2bf(in[(size_t)r * C + c]);
}

// ---- pre-pass: expand rel-pos bias to [head][q=49][k=64] f32, zero-padded ----
__global__ __launch_bounds__(256)
void expand_bias_pad(const float* __restrict__ bt, float* __restrict__ bx) {
  const int i = blockIdx.x * 256 + threadIdx.x;
  if (i >= NHEADS * 49 * 64) return;
  const int head = i / (49 * 64);
  const int rem = i % (49 * 64);
  const int q = rem / 64, k = rem % 64;
  float v = 0.f;
  if (k < 49) {
    const int idx = (q / 7 - k / 7 + 6) * 13 + (q % 7 - k % 7 + 6);
    v = bt[idx * NHEADS + head];
  }
  bx[i] = v;
}

// ---- R4-structure GEMM + T2 swizzle, templated BK: C = A[M][K] @ Bt[N][K]^T
// 128x128 tile, 4 waves (64x64 each), single LDS buffer, 2 barriers/K-step,
// pure global_load_lds staging (pre-swizzled source + XOR'd reads), XCD
// swizzle. BK=128 halves the barrier-drain count (occupancy already
// AGPR-capped at ~2 blocks/CU, so 64 KB LDS is ~free).
template<bool OUT_F32_BIAS, int BK>
__global__ __launch_bounds__(256)
void gemm_bt(const ushort* __restrict__ A, const ushort* __restrict__ Bt,
             const float* __restrict__ bias, void* __restrict__ Cp,
             const int N, const int K, const int nbx)
{
  __shared__ ushort As[128 * BK];
  __shared__ ushort Bs[128 * BK];
  constexpr int UNITS = BK / 8;          // 16B units per row
  constexpr int ROUNDS = (128 * BK) / (256 * 8);  // staging rounds per operand

  const int tid = threadIdx.x;
  const int lane = tid & 63;
  const int wave = tid >> 6;
  const int wm = wave >> 1, wn = wave & 1;
  const int l15 = lane & 15, l16 = lane >> 4;

  int bid = blockIdx.x;
  const int nwg = gridDim.x;
  if ((nwg & 7) == 0) bid = (bid & 7) * (nwg >> 3) + (bid >> 3);
  const int row0 = (bid / nbx) * 128;
  const int col0 = (bid % nbx) * 128;

  f32x4 acc[4][4] = {};

  for (int ko = 0; ko < K; ko += BK) {
    if (ko) __syncthreads();
    #pragma unroll
    for (int it = 0; it < ROUNDS; ++it) {
      const int chunk = it * 4 + wave;
      const int idx = chunk * 64 + lane;
      const int m = idx / UNITS;                       // tile row 0..127
      const int u = idx % UNITS;                       // 16B unit in row
      const int k8 = ((u ^ (m & 7)) * 8);              // inverse-swizzled source
      gload_lds16(A + (size_t)(row0 + m) * K + ko + k8, &As[chunk * 512]);
      gload_lds16(Bt + (size_t)(col0 + m) * K + ko + k8, &Bs[chunk * 512]);
    }
    __syncthreads();
    #pragma unroll
    for (int kk = 0; kk < BK; kk += 32) {
      bhalf8 af[4], bfr[4];
      #pragma unroll
      for (int f = 0; f < 4; ++f) {
        const int ra = wm * 64 + f * 16 + l15;
        const int rb = wn * 64 + f * 16 + l15;
        const int kb = (kk + l16 * 8) * 2;
        af[f]  = *(const bhalf8*)((const char*)As + ra * (BK * 2) + (kb ^ ((ra & 7) << 4)));
        bfr[f] = *(const bhalf8*)((const char*)Bs + rb * (BK * 2) + (kb ^ ((rb & 7) << 4)));
      }
      #pragma unroll
      for (int fm = 0; fm < 4; ++fm)
        #pragma unroll
        for (int fn = 0; fn < 4; ++fn)
          acc[fm][fn] = __builtin_amdgcn_mfma_f32_16x16x32_bf16(af[fm], bfr[fn], acc[fm][fn], 0, 0, 0);
    }
  }

  #pragma unroll
  for (int fm = 0; fm < 4; ++fm) {
    const int rb = row0 + wm * 64 + fm * 16 + l16 * 4;
    #pragma unroll
    for (int fn = 0; fn < 4; ++fn) {
      const int cc = col0 + wn * 64 + fn * 16 + l15;
      const float badd = OUT_F32_BIAS ? bias[cc] : 0.f;
      #pragma unroll
      for (int i = 0; i < 4; ++i) {
        const float vv = acc[fm][fn][i] + badd;
        if (OUT_F32_BIAS) ((float*)Cp)[(size_t)(rb + i) * N + cc] = vv;
        else ((ushort*)Cp)[(size_t)(rb + i) * N + cc] = f2bf(vv);
      }
    }
  }
}

// ---- window attention v4 + T5 setprio: swapped QK^T softmax (R21-exact) ----
__global__ __launch_bounds__(256)
void win_attn4(const ushort* __restrict__ qkv, const float* __restrict__ biasx,
               ushort* __restrict__ attn_out)
{
  __shared__ ushort VtAll[4][32 * 64];   // [d][t] swizzled
  __shared__ ushort PsAll[4][64 * 64];   // [q][k] swizzled

  const int tid = threadIdx.x;
  const int lane = tid & 63, wave = tid >> 6;
  const int l15 = lane & 15, l16 = lane >> 4;
  const int gid = blockIdx.x * 4 + wave;
  const int head = gid % NHEADS;
  const int win = gid / NHEADS;
  const int b = win >> 6, wi = (win >> 3) & 7, wj = win & 7;
  char* Vt = (char*)VtAll[wave];
  char* Ps = (char*)PsAll[wave];

  const int base_row = b * 3136 + wi * 7 * 56 + wj * 7;

  // ---- V stage: coalesced 16B loads, swizzled transposed LDS writes ----
  #pragma unroll
  for (int it = 0; it < 4; ++it) {
    const int t = lane;
    const int d0 = it * 8;
    bhalf8 v = {0, 0, 0, 0, 0, 0, 0, 0};
    if (t < 49) {
      const size_t off = (size_t)(base_row + (t / 7) * 56 + (t % 7)) * NQKV
                         + 768 + head * HDIM + d0;
      v = *(const bhalf8*)(qkv + off);
    }
    #pragma unroll
    for (int j = 0; j < 8; ++j) {
      const int d = d0 + j;
      const int byteoff = ((d * 64 + t) * 2) ^ ((d & 7) << 4);
      *(ushort*)(Vt + byteoff) = (ushort)v[j];
    }
  }

  // ---- Q/K fragments direct from global ----
  bhalf8 qf[4], kf[4];
  #pragma unroll
  for (int f = 0; f < 4; ++f) {
    const int r = f * 16 + l15;
    const int rr = r < 49 ? r : 48;
    const size_t off = (size_t)(base_row + (rr / 7) * 56 + (rr % 7)) * NQKV
                       + head * HDIM + l16 * 8;
    qf[f] = *(const bhalf8*)(qkv + off);
    kf[f] = *(const bhalf8*)(qkv + off + 384);
  }

  // ---- S^T = K @ Q^T (swapped): s[fm][fn][i] = S[q=fn*16+l15][k=fm*16+l16*4+i]
  const f32x4 fz = {};
  f32x4 s[4][4];
  __builtin_amdgcn_s_setprio(1);
  #pragma unroll
  for (int fm = 0; fm < 4; ++fm)
    #pragma unroll
    for (int fn = 0; fn < 4; ++fn)
      s[fm][fn] = __builtin_amdgcn_mfma_f32_16x16x32_bf16(kf[fm], qf[fn], fz, 0, 0, 0);
  __builtin_amdgcn_s_setprio(0);

  const float scale = 0.17677669529663687f;
  const float* bq = biasx + (size_t)head * (49 * 64);

  #pragma unroll
  for (int fn = 0; fn < 4; ++fn) {
    const int q = fn * 16 + l15;
    const int xr = (q & 7) << 4;
    char* prow = Ps + q * 128;
    if (fn == 3 && l15 != 0) {
      // q >= 49: zero the whole Ps row slice owned by this lane
      #pragma unroll
      for (int fm = 0; fm < 4; ++fm) {
        const int b0 = (fm * 16 + l16 * 4) * 2;
        *(uint32_t*)(prow + (b0 ^ xr)) = 0u;
        *(uint32_t*)(prow + (b0 ^ xr) + 4) = 0u;
      }
    } else {
      float e[4][4];
      float local = 0.f;
      #pragma unroll
      for (int fm = 0; fm < 3; ++fm)    // k = fm*16+l16*4+i <= 47 < 49: all valid
        #pragma unroll
        for (int i = 0; i < 4; ++i) {
          e[fm][i] = __expf(s[fm][fn][i] * scale);
          local += e[fm][i];
        }
      e[3][0] = e[3][1] = e[3][2] = e[3][3] = 0.f;
      if (l16 == 0) {                   // k = 48 is the only valid fm=3 slot
        e[3][0] = __expf(s[3][fn][0] * scale);
        local += e[3][0];
      }
      float sum = local + __shfl_xor(local, 16);
      sum += __shfl_xor(sum, 32);
      const float inv = __builtin_amdgcn_rcpf(sum);
      const float* b4p = bq + q * 64;
      #pragma unroll
      for (int fm = 0; fm < 4; ++fm) {
        const int k0 = fm * 16 + l16 * 4;
        const float4 b4 = *(const float4*)(b4p + k0);  // 16B-aligned, pad zeros
        const uint32_t w0 = cvtpk(fmaf(e[fm][0], inv, b4.x),
                                  fmaf(e[fm][1], inv, b4.y));
        const uint32_t w1 = cvtpk(fmaf(e[fm][2], inv, b4.z),
                                  fmaf(e[fm][3], inv, b4.w));
        const int b0 = (k0 * 2) ^ xr;
        *(uint32_t*)(prow + b0) = w0;
        *(uint32_t*)(prow + b0 + 4) = w1;
      }
    }
  }

  // ---- O = P @ V ----
  f32x4 o[4][2] = {};
  #pragma unroll
  for (int kk = 0; kk < 64; kk += 32) {
    bhalf8 pf[4], vf[2];
    #pragma unroll
    for (int f = 0; f < 4; ++f) {
      const int r = f * 16 + l15;
      pf[f] = *(const bhalf8*)(Ps + (((r * 64 + kk + l16 * 8) * 2) ^ ((r & 7) << 4)));
    }
    #pragma unroll
    for (int f = 0; f < 2; ++f) {
      const int d = f * 16 + l15;
      vf[f] = *(const bhalf8*)(Vt + (((d * 64 + kk + l16 * 8) * 2) ^ ((d & 7) << 4)));
    }
    __builtin_amdgcn_s_setprio(1);
    #pragma unroll
    for (int fm = 0; fm < 4; ++fm)
      #pragma unroll
      for (int fn = 0; fn < 2; ++fn)
        o[fm][fn] = __builtin_amdgcn_mfma_f32_16x16x32_bf16(pf[fm], vf[fn], o[fm][fn], 0, 0, 0);
    __builtin_amdgcn_s_setprio(0);
  }

  // ---- store O ----
  #pragma unroll
  for (int fm = 0; fm < 4; ++fm) {
    #pragma unroll
    for (int i = 0; i < 4; ++i) {
      const int r = fm * 16 + l16 * 4 + i;
      if (r < 49) {
        const int grow = base_row + (r / 7) * 56 + (r % 7);
        #pragma unroll
        for (int fn = 0; fn < 2; ++fn) {
          const int d = fn * 16 + l15;
          attn_out[(size_t)grow * HID + head * HDIM + d] = f2bf(o[fm][fn][i]);
        }
      }
    }
  }
}

extern "C" void kernel_launch(void* const* d_in, const int* in_sizes, int n_in,
                              void* d_out, int out_size, void* d_ws, size_t ws_size,
                              hipStream_t stream) {
  const float* x          = (const float*)d_in[0];
  const float* w_qkv      = (const float*)d_in[1];
  const float* w_out      = (const float*)d_in[2];
  const float* b_out      = (const float*)d_in[3];
  const float* bias_table = (const float*)d_in[4];
  float* out = (float*)d_out;

  // ws layout (ushorts): xb | qkv | wqkvT | woutT | biasx(f32 padded)
  ushort* xb     = (ushort*)d_ws;                       // [TOK][384]  bf16
  ushort* qkv    = xb + (size_t)TOK * HID;              // [TOK][1152] bf16
  ushort* wqkvT  = qkv + (size_t)TOK * NQKV;            // [1152][384] bf16
  ushort* woutT  = wqkvT + (size_t)NQKV * HID;          // [384][384]  bf16
  float*  biasx  = (float*)(woutT + (size_t)HID * HID); // [12][49][64] f32
  ushort* attn_o = xb;                                  // alias (xb dead after GEMM1)

  // 0) conversions
  {
    const int n8 = TOK * HID / 8;
    cvt_bf16<<<dim3((n8 + 255) / 256), dim3(256), 0, stream>>>(x, xb, n8);
    transpose_cvt<<<dim3(HID * NQKV / 256), dim3(256), 0, stream>>>(w_qkv, wqkvT, HID, NQKV);
    transpose_cvt<<<dim3(HID * HID / 256), dim3(256), 0, stream>>>(w_out, woutT, HID, HID);
    expand_bias_pad<<<dim3((NHEADS * 49 * 64 + 255) / 256), dim3(256), 0, stream>>>(
        bias_table, biasx);
  }

  // 1) qkv = xb @ wqkvT^T  (M=100352, N=1152, K=384), BK=128 (3 K-steps)
  gemm_bt<false, 128><<<dim3((NQKV / 128) * (TOK / 128)), dim3(256), 0, stream>>>(
      xb, wqkvT, nullptr, qkv, NQKV, HID, NQKV / 128);

  // 2) window attention v4 + setprio
  win_attn4<<<dim3(2048 * NHEADS / 4), dim3(256), 0, stream>>>(qkv, biasx, attn_o);

  // 3) out = attn_o @ woutT^T + b_out  (fp32 out), BK=64 (frozen)
  gemm_bt<true, 64><<<dim3((HID / 128) * (TOK / 128)), dim3(256), 0, stream>>>(
      attn_o, woutT, b_out, out, HID, HID, HID / 128);
}

// Round 23
// 330.133 us; speedup vs baseline: 1.0572x; 1.0572x over previous
//
#include <hip/hip_runtime.h>
#include <hip/hip_bf16.h>
#include <cstdint>

#define TOK 100352
#define HID 384
#define NQKV 1152
#define NHEADS 12
#define HDIM 32

typedef __attribute__((ext_vector_type(8))) short bhalf8;
typedef __attribute__((ext_vector_type(4))) float f32x4;

__device__ __forceinline__ ushort f2bf(float f) {
  uint32_t u = __float_as_uint(f);
  return (ushort)((u + 0x7FFFu + ((u >> 16) & 1u)) >> 16);
}

__device__ __forceinline__ void gload_lds16(const ushort* g, ushort* l) {
  __builtin_amdgcn_global_load_lds(
      (const __attribute__((address_space(1))) unsigned int*)g,
      (__attribute__((address_space(3))) unsigned int*)l, 16, 0, 0);
}

__device__ __forceinline__ uint32_t cvtpk(float a, float b) {
  uint32_t r;
  asm("v_cvt_pk_bf16_f32 %0, %1, %2" : "=v"(r) : "v"(a), "v"(b));
  return r;
}

// ---- pre-pass: fp32 -> bf16, vectorized 8/thread ----
__global__ __launch_bounds__(256)
void cvt_bf16(const float* __restrict__ in, ushort* __restrict__ out, const int n8) {
  const int i = blockIdx.x * 256 + threadIdx.x;
  if (i >= n8) return;
  const float4 f0 = ((const float4*)in)[(size_t)i * 2];
  const float4 f1 = ((const float4*)in)[(size_t)i * 2 + 1];
  bhalf8 v;
  v[0] = (short)f2bf(f0.x); v[1] = (short)f2bf(f0.y);
  v[2] = (short)f2bf(f0.z); v[3] = (short)f2bf(f0.w);
  v[4] = (short)f2bf(f1.x); v[5] = (short)f2bf(f1.y);
  v[6] = (short)f2bf(f1.z); v[7] = (short)f2bf(f1.w);
  ((bhalf8*)out)[i] = v;
}

// ---- pre-pass: [R][C] fp32 -> [C][R] bf16 (tiny weights) ----
__global__ __launch_bounds__(256)
void transpose_cvt(const float* __restrict__ in, ushort* __restrict__ out,
                   const int R, const int C) {
  const int i = blockIdx.x * 256 + threadIdx.x;
  if (i >= R * C) return;
  const int r = i % R, c = i / R;
  out[i] = f2bf(in[(size_t)r * C + c]);
}

// ---- pre-pass: expand rel-pos bias to [head][q=49][k=64] f32, zero-padded ----
__global__ __launch_bounds__(256)
void expand_bias_pad(const float* __restrict__ bt, float* __restrict__ bx) {
  const int i = blockIdx.x * 256 + threadIdx.x;
  if (i >= NHEADS * 49 * 64) return;
  const int head = i / (49 * 64);
  const int rem = i % (49 * 64);
  const int q = rem / 64, k = rem % 64;
  float v = 0.f;
  if (k < 49) {
    const int idx = (q / 7 - k / 7 + 6) * 13 + (q % 7 - k % 7 + 6);
    v = bt[idx * NHEADS + head];
  }
  bx[i] = v;
}

// ---- R4-exact GEMM + T2 swizzle: C = A[M][K] @ Bt[N][K]^T ----
// 128x128 tile, 4 waves (64x64 each), single LDS buffer, 2 barriers/K-step,
// pure global_load_lds staging (pre-swizzled source + XOR'd reads), XCD
// swizzle. BK=64: best of 9 structural variants tried (dbuf, counted-vmcnt,
// 256-tiles, 4-phase template, BK=128 all regressed at K=384's short loop).
template<bool OUT_F32_BIAS>
__global__ __launch_bounds__(256)
void gemm_bt(const ushort* __restrict__ A, const ushort* __restrict__ Bt,
             const float* __restrict__ bias, void* __restrict__ Cp,
             const int N, const int K, const int nbx)
{
  __shared__ ushort As[128 * 64];
  __shared__ ushort Bs[128 * 64];

  const int tid = threadIdx.x;
  const int lane = tid & 63;
  const int wave = tid >> 6;
  const int wm = wave >> 1, wn = wave & 1;
  const int l15 = lane & 15, l16 = lane >> 4;

  int bid = blockIdx.x;
  const int nwg = gridDim.x;
  if ((nwg & 7) == 0) bid = (bid & 7) * (nwg >> 3) + (bid >> 3);
  const int row0 = (bid / nbx) * 128;
  const int col0 = (bid % nbx) * 128;

  f32x4 acc[4][4] = {};

  for (int ko = 0; ko < K; ko += 64) {
    if (ko) __syncthreads();
    #pragma unroll
    for (int it = 0; it < 4; ++it) {
      const int chunk = it * 4 + wave;
      const int idx = chunk * 64 + lane;
      const int m = idx >> 3;
      const int k8 = (((idx & 7) ^ (m & 7)) * 8);
      gload_lds16(A + (size_t)(row0 + m) * K + ko + k8, &As[chunk * 512]);
      gload_lds16(Bt + (size_t)(col0 + m) * K + ko + k8, &Bs[chunk * 512]);
    }
    __syncthreads();
    #pragma unroll
    for (int kk = 0; kk < 64; kk += 32) {
      bhalf8 af[4], bfr[4];
      #pragma unroll
      for (int f = 0; f < 4; ++f) {
        const int ra = wm * 64 + f * 16 + l15;
        const int rb = wn * 64 + f * 16 + l15;
        const int kb = (kk + l16 * 8) * 2;
        af[f]  = *(const bhalf8*)((const char*)As + ra * 128 + (kb ^ ((ra & 7) << 4)));
        bfr[f] = *(const bhalf8*)((const char*)Bs + rb * 128 + (kb ^ ((rb & 7) << 4)));
      }
      #pragma unroll
      for (int fm = 0; fm < 4; ++fm)
        #pragma unroll
        for (int fn = 0; fn < 4; ++fn)
          acc[fm][fn] = __builtin_amdgcn_mfma_f32_16x16x32_bf16(af[fm], bfr[fn], acc[fm][fn], 0, 0, 0);
    }
  }

  #pragma unroll
  for (int fm = 0; fm < 4; ++fm) {
    const int rb = row0 + wm * 64 + fm * 16 + l16 * 4;
    #pragma unroll
    for (int fn = 0; fn < 4; ++fn) {
      const int cc = col0 + wn * 64 + fn * 16 + l15;
      const float badd = OUT_F32_BIAS ? bias[cc] : 0.f;
      #pragma unroll
      for (int i = 0; i < 4; ++i) {
        const float vv = acc[fm][fn][i] + badd;
        if (OUT_F32_BIAS) ((float*)Cp)[(size_t)(rb + i) * N + cc] = vv;
        else ((ushort*)Cp)[(size_t)(rb + i) * N + cc] = f2bf(vv);
      }
    }
  }
}

// ---- window attention v4 + T5 setprio: swapped QK^T softmax ----
// S^T = mfma(K, Q): lane holds q = fn*16+l15, k = fm*16+l16*4+i.
// Row-sum = 15 adds + 2 shfl; bias = aligned float4 from padded [h][q][64];
// P packed to Ps via cvt_pk (32 x ds_write_b32). Blocks = 4 independent
// waves (no barriers) -> m191's setprio-positive regime.
__global__ __launch_bounds__(256)
void win_attn4(const ushort* __restrict__ qkv, const float* __restrict__ biasx,
               ushort* __restrict__ attn_out)
{
  __shared__ ushort VtAll[4][32 * 64];   // [d][t] swizzled
  __shared__ ushort PsAll[4][64 * 64];   // [q][k] swizzled

  const int tid = threadIdx.x;
  const int lane = tid & 63, wave = tid >> 6;
  const int l15 = lane & 15, l16 = lane >> 4;
  const int gid = blockIdx.x * 4 + wave;
  const int head = gid % NHEADS;
  const int win = gid / NHEADS;
  const int b = win >> 6, wi = (win >> 3) & 7, wj = win & 7;
  char* Vt = (char*)VtAll[wave];
  char* Ps = (char*)PsAll[wave];

  const int base_row = b * 3136 + wi * 7 * 56 + wj * 7;

  // ---- V stage: coalesced 16B loads, swizzled transposed LDS writes ----
  #pragma unroll
  for (int it = 0; it < 4; ++it) {
    const int t = lane;
    const int d0 = it * 8;
    bhalf8 v = {0, 0, 0, 0, 0, 0, 0, 0};
    if (t < 49) {
      const size_t off = (size_t)(base_row + (t / 7) * 56 + (t % 7)) * NQKV
                         + 768 + head * HDIM + d0;
      v = *(const bhalf8*)(qkv + off);
    }
    #pragma unroll
    for (int j = 0; j < 8; ++j) {
      const int d = d0 + j;
      const int byteoff = ((d * 64 + t) * 2) ^ ((d & 7) << 4);
      *(ushort*)(Vt + byteoff) = (ushort)v[j];
    }
  }

  // ---- Q/K fragments direct from global ----
  bhalf8 qf[4], kf[4];
  #pragma unroll
  for (int f = 0; f < 4; ++f) {
    const int r = f * 16 + l15;
    const int rr = r < 49 ? r : 48;
    const size_t off = (size_t)(base_row + (rr / 7) * 56 + (rr % 7)) * NQKV
                       + head * HDIM + l16 * 8;
    qf[f] = *(const bhalf8*)(qkv + off);
    kf[f] = *(const bhalf8*)(qkv + off + 384);
  }

  // ---- S^T = K @ Q^T (swapped): s[fm][fn][i] = S[q=fn*16+l15][k=fm*16+l16*4+i]
  const f32x4 fz = {};
  f32x4 s[4][4];
  __builtin_amdgcn_s_setprio(1);
  #pragma unroll
  for (int fm = 0; fm < 4; ++fm)
    #pragma unroll
    for (int fn = 0; fn < 4; ++fn)
      s[fm][fn] = __builtin_amdgcn_mfma_f32_16x16x32_bf16(kf[fm], qf[fn], fz, 0, 0, 0);
  __builtin_amdgcn_s_setprio(0);

  const float scale = 0.17677669529663687f;
  const float* bq = biasx + (size_t)head * (49 * 64);

  #pragma unroll
  for (int fn = 0; fn < 4; ++fn) {
    const int q = fn * 16 + l15;
    const int xr = (q & 7) << 4;
    char* prow = Ps + q * 128;
    if (fn == 3 && l15 != 0) {
      // q >= 49: zero the whole Ps row slice owned by this lane
      #pragma unroll
      for (int fm = 0; fm < 4; ++fm) {
        const int b0 = (fm * 16 + l16 * 4) * 2;
        *(uint32_t*)(prow + (b0 ^ xr)) = 0u;
        *(uint32_t*)(prow + (b0 ^ xr) + 4) = 0u;
      }
    } else {
      float e[4][4];
      float local = 0.f;
      #pragma unroll
      for (int fm = 0; fm < 3; ++fm)    // k = fm*16+l16*4+i <= 47 < 49: all valid
        #pragma unroll
        for (int i = 0; i < 4; ++i) {
          e[fm][i] = __expf(s[fm][fn][i] * scale);
          local += e[fm][i];
        }
      e[3][0] = e[3][1] = e[3][2] = e[3][3] = 0.f;
      if (l16 == 0) {                   // k = 48 is the only valid fm=3 slot
        e[3][0] = __expf(s[3][fn][0] * scale);
        local += e[3][0];
      }
      float sum = local + __shfl_xor(local, 16);
      sum += __shfl_xor(sum, 32);
      const float inv = __builtin_amdgcn_rcpf(sum);
      const float* b4p = bq + q * 64;
      #pragma unroll
      for (int fm = 0; fm < 4; ++fm) {
        const int k0 = fm * 16 + l16 * 4;
        const float4 b4 = *(const float4*)(b4p + k0);  // 16B-aligned, pad zeros
        const uint32_t w0 = cvtpk(fmaf(e[fm][0], inv, b4.x),
                                  fmaf(e[fm][1], inv, b4.y));
        const uint32_t w1 = cvtpk(fmaf(e[fm][2], inv, b4.z),
                                  fmaf(e[fm][3], inv, b4.w));
        const int b0 = (k0 * 2) ^ xr;
        *(uint32_t*)(prow + b0) = w0;
        *(uint32_t*)(prow + b0 + 4) = w1;
      }
    }
  }

  // ---- O = P @ V ----
  f32x4 o[4][2] = {};
  #pragma unroll
  for (int kk = 0; kk < 64; kk += 32) {
    bhalf8 pf[4], vf[2];
    #pragma unroll
    for (int f = 0; f < 4; ++f) {
      const int r = f * 16 + l15;
      pf[f] = *(const bhalf8*)(Ps + (((r * 64 + kk + l16 * 8) * 2) ^ ((r & 7) << 4)));
    }
    #pragma unroll
    for (int f = 0; f < 2; ++f) {
      const int d = f * 16 + l15;
      vf[f] = *(const bhalf8*)(Vt + (((d * 64 + kk + l16 * 8) * 2) ^ ((d & 7) << 4)));
    }
    __builtin_amdgcn_s_setprio(1);
    #pragma unroll
    for (int fm = 0; fm < 4; ++fm)
      #pragma unroll
      for (int fn = 0; fn < 2; ++fn)
        o[fm][fn] = __builtin_amdgcn_mfma_f32_16x16x32_bf16(pf[fm], vf[fn], o[fm][fn], 0, 0, 0);
    __builtin_amdgcn_s_setprio(0);
  }

  // ---- store O ----
  #pragma unroll
  for (int fm = 0; fm < 4; ++fm) {
    #pragma unroll
    for (int i = 0; i < 4; ++i) {
      const int r = fm * 16 + l16 * 4 + i;
      if (r < 49) {
        const int grow = base_row + (r / 7) * 56 + (r % 7);
        #pragma unroll
        for (int fn = 0; fn < 2; ++fn) {
          const int d = fn * 16 + l15;
          attn_out[(size_t)grow * HID + head * HDIM + d] = f2bf(o[fm][fn][i]);
        }
      }
    }
  }
}

extern "C" void kernel_launch(void* const* d_in, const int* in_sizes, int n_in,
                              void* d_out, int out_size, void* d_ws, size_t ws_size,
                              hipStream_t stream) {
  const float* x          = (const float*)d_in[0];
  const float* w_qkv      = (const float*)d_in[1];
  const float* w_out      = (const float*)d_in[2];
  const float* b_out      = (const float*)d_in[3];
  const float* bias_table = (const float*)d_in[4];
  float* out = (float*)d_out;

  // ws layout (ushorts): xb | qkv | wqkvT | woutT | biasx(f32 padded)
  ushort* xb     = (ushort*)d_ws;                       // [TOK][384]  bf16
  ushort* qkv    = xb + (size_t)TOK * HID;              // [TOK][1152] bf16
  ushort* wqkvT  = qkv + (size_t)TOK * NQKV;            // [1152][384] bf16
  ushort* woutT  = wqkvT + (size_t)NQKV * HID;          // [384][384]  bf16
  float*  biasx  = (float*)(woutT + (size_t)HID * HID); // [12][49][64] f32
  ushort* attn_o = xb;                                  // alias (xb dead after GEMM1)

  // 0) conversions
  {
    const int n8 = TOK * HID / 8;
    cvt_bf16<<<dim3((n8 + 255) / 256), dim3(256), 0, stream>>>(x, xb, n8);
    transpose_cvt<<<dim3(HID * NQKV / 256), dim3(256), 0, stream>>>(w_qkv, wqkvT, HID, NQKV);
    transpose_cvt<<<dim3(HID * HID / 256), dim3(256), 0, stream>>>(w_out, woutT, HID, HID);
    expand_bias_pad<<<dim3((NHEADS * 49 * 64 + 255) / 256), dim3(256), 0, stream>>>(
        bias_table, biasx);
  }

  // 1) qkv = xb @ wqkvT^T  (M=100352, N=1152, K=384)
  gemm_bt<false><<<dim3((NQKV / 128) * (TOK / 128)), dim3(256), 0, stream>>>(
      xb, wqkvT, nullptr, qkv, NQKV, HID, NQKV / 128);

  // 2) window attention v4 + setprio
  win_attn4<<<dim3(2048 * NHEADS / 4), dim3(256), 0, stream>>>(qkv, biasx, attn_o);

  // 3) out = attn_o @ woutT^T + b_out  (fp32 out)
  gemm_bt<true><<<dim3((HID / 128) * (TOK / 128)), dim3(256), 0, stream>>>(
      attn_o, woutT, b_out, out, HID, HID, HID / 128);
}